// Round 9
// baseline (192.965 us; speedup 1.0000x reference)
//
#include <hip/hip_runtime.h>
#include <hip/hip_bf16.h>

// CausalGraphLayer: out = [D^-1/2 (A+I) D^-1/2 (x W) + b] @ softmax(CA)
// Folded: M = W @ softmax(CA); bs = b @ softmax(CA);
//         z[i] = dinv[i] * (x[i] @ M)   (stored bf16)
//         out[d] = dinv[d] * (z[d] + sum_{(s,d) in E} z[s]) + bs
// N = 100000, E = 1600000, D = 64.
//
// Round 21: nontemporal streams. Rounds 7-8 (TLP x2, MLP x2) both null
// => kernels are THROUGHPUT-bound, not latency-bound. Remaining
// mechanisms: (a) bin's scattered 4B writes (16B mean runs) force
// read-for-ownership RMW on ~every arena line; (b) stream-once data
// (src/dst, binned) evicts L2 capacity needed for write-combining and
// for sg's zbf working set (12.8MB vs 4MB/XCD -> 90MB HBM refetch).
// Fix: __builtin_nontemporal_{load,store} on all stream-once int data:
//   bin : nt-load src/dst, nt-store binned scatter.
//   zmat: nt-load binned (histogram pass).
//   sg  : nt-load binned (stage pass).
// Numerics untouched -> absmax bit-identical. If this is null too, the
// owned pipeline is at its random-access floor and next round declares
// roofline.
// prep v2 / bin v4 / zmat v3 / sg v2 structure verbatim from round 20.

#define D 64
#define BSHIFT 6
#define BNODES 64        // nodes per bucket
#define ARENA_CAP 1728   // arena slots per bucket (mean 1024, +22 sigma)
#define BIN_TILE 8192    // bin edges per block (196 blocks)

// f32 -> bf16 (round to nearest even)
__device__ __forceinline__ unsigned short f2bf(float f) {
    union { float f; unsigned int u; } c;
    c.f = f;
    unsigned int u = c.u;
    u += 0x7fffu + ((u >> 16) & 1u);
    return (unsigned short)(u >> 16);
}
// low/high bf16 of a packed uint -> f32
__device__ __forceinline__ float bflo(unsigned int u) {
    union { unsigned int u; float f; } c;
    c.u = u << 16;
    return c.f;
}
__device__ __forceinline__ float bfhi(unsigned int u) {
    union { unsigned int u; float f; } c;
    c.u = u & 0xffff0000u;
    return c.f;
}

// ---------------- K1: prep v2 — S = softmax(A); M = W@S; bs = b@S -----------
__global__ __launch_bounds__(256) void prep_kernel(const float* __restrict__ W,
                                                   const float* __restrict__ b,
                                                   const float* __restrict__ A,
                                                   float* __restrict__ M,
                                                   float* __restrict__ bs,
                                                   int* __restrict__ cursor, int nbuck) {
    __shared__ float S[D * D];
    int t = threadIdx.x;
    int gidx = blockIdx.x * 256 + t;
    if (gidx < nbuck) cursor[gidx] = gidx * ARENA_CAP;  // arena base
    int wv = t >> 6, lane = t & 63;
#pragma unroll 4
    for (int rr = 0; rr < 16; rr++) {
        int r = wv * 16 + rr;
        float a = A[r * D + lane];
        float m = a;
        for (int off = 32; off; off >>= 1) m = fmaxf(m, __shfl_xor(m, off));
        float p = __expf(a - m);
        float ssum = p;
        for (int off = 32; off; off >>= 1) ssum += __shfl_xor(ssum, off);
        S[r * D + lane] = p / ssum;
    }
    __syncthreads();
    int k = blockIdx.x * 4 + wv;  // M row (wave-uniform)
    float acc = 0.f;
    for (int d2 = 0; d2 < D; d2++) acc += W[k * D + d2] * S[d2 * D + lane];
    M[k * D + lane] = acc;
    if (blockIdx.x == 0 && t < D) {
        float a2 = 0.f;
        for (int d2 = 0; d2 < D; d2++) a2 += b[d2] * S[d2 * D + t];
        bs[t] = a2;
    }
}

// ---------------- K2: bin v5 — nt streams + nt scatter -----------------------
__global__ __launch_bounds__(1024) void bin_kernel(const int* __restrict__ src,
                                                   const int* __restrict__ dst,
                                                   int* __restrict__ cursor,
                                                   int* __restrict__ binned, int E) {
    __shared__ int h[2048];
    int t = threadIdx.x;
    for (int i = t; i < 2048; i += 1024) h[i] = 0;
    __syncthreads();
    int base = blockIdx.x * BIN_TILE;
    int pv[8], bk[8], rv[8];
#pragma unroll
    for (int k = 0; k < 8; k++) {
        int e = base + k * 1024 + t;
        if (e < E) {
            int s = __builtin_nontemporal_load(&src[e]);
            int d = __builtin_nontemporal_load(&dst[e]);
            bk[k] = (d >> BSHIFT) & 2047;
            pv[k] = (s << BSHIFT) | (d & (BNODES - 1));  // packed: src<<6 | dlocal
            rv[k] = atomicAdd(&h[bk[k]], 1);             // rank within (block,bucket)
        }
    }
    __syncthreads();
    for (int b2 = t; b2 < 2048; b2 += 1024) {
        int c = h[b2];
        if (c) h[b2] = atomicAdd(&cursor[b2], c);  // h[b2] := global write base
    }
    __syncthreads();
#pragma unroll
    for (int k = 0; k < 8; k++) {
        int e = base + k * 1024 + t;
        if (e < E)
            __builtin_nontemporal_store(pv[k], &binned[h[bk[k]] + rv[k]]);
    }
}

// ---------------- K3: zmat v3 — z = dinv*(x@M), fused degree histogram ------
__device__ __forceinline__ void fma4(float4& a, float xv, const float4& m) {
    a.x += xv * m.x; a.y += xv * m.y; a.z += xv * m.z; a.w += xv * m.w;
}
__global__ __launch_bounds__(128) void zmat_kernel(const float* __restrict__ x,
                                                   const float* __restrict__ M,
                                                   const int* __restrict__ binned,
                                                   const int* __restrict__ cursor,
                                                   unsigned short* __restrict__ zbf,
                                                   int N) {
    __shared__ float xs[64][D + 4];  // 17.4 KB
    __shared__ int h[BNODES];
    int t = threadIdx.x;
    int b = blockIdx.x;
    int row0 = b << 6;
    if (t < BNODES) h[t] = 0;
    __syncthreads();
    int abase = b * ARENA_CAP;
    int cnt = cursor[b] - abase;
    if (cnt > ARENA_CAP) cnt = ARENA_CAP;
    for (int i = t; i < cnt; i += 128)
        atomicAdd(&h[__builtin_nontemporal_load(&binned[abase + i]) & (BNODES - 1)], 1);
    for (int w = t; w < 1024; w += 128) {
        int r = w >> 4, c4 = (w & 15) << 2;
        int row = row0 + r;
        float4 v = make_float4(0.f, 0.f, 0.f, 0.f);
        if (row < N) v = *(const float4*)&x[(size_t)row * D + c4];
        *(float4*)&xs[r][c4] = v;
    }
    __syncthreads();
    int cg = t & 15, rg = t >> 4;    // rg 0..7
    int r0 = rg << 3, c0 = cg << 2;  // 8 rows, 4 cols per thread
    float4 acc[8];
#pragma unroll
    for (int rr = 0; rr < 8; rr++) acc[rr] = make_float4(0.f, 0.f, 0.f, 0.f);
#pragma unroll 2
    for (int k = 0; k < D; k += 4) {
        float4 m0 = *(const float4*)&M[(k + 0) * D + c0];
        float4 m1 = *(const float4*)&M[(k + 1) * D + c0];
        float4 m2 = *(const float4*)&M[(k + 2) * D + c0];
        float4 m3 = *(const float4*)&M[(k + 3) * D + c0];
#pragma unroll
        for (int rr = 0; rr < 8; rr++) {
            float4 xv = *(const float4*)&xs[r0 + rr][k];
            fma4(acc[rr], xv.x, m0);
            fma4(acc[rr], xv.y, m1);
            fma4(acc[rr], xv.z, m2);
            fma4(acc[rr], xv.w, m3);
        }
    }
#pragma unroll
    for (int rr = 0; rr < 8; rr++) {
        int row = row0 + r0 + rr;
        if (row < N) {
            float di = rsqrtf((float)(h[r0 + rr] + 1));
            ushort4 s;
            s.x = f2bf(di * acc[rr].x);
            s.y = f2bf(di * acc[rr].y);
            s.z = f2bf(di * acc[rr].z);
            s.w = f2bf(di * acc[rr].w);
            *(ushort4*)&zbf[(size_t)row * D + c0] = s;
        }
    }
}

// ---------------- K4: sg v2 — fused LDS sort + 8-in-flight gather -----------
__global__ __launch_bounds__(256) void sg_kernel(const unsigned short* __restrict__ zbf,
                                                 const int* __restrict__ binned,
                                                 const int* __restrict__ cursor,
                                                 const float* __restrict__ bs,
                                                 float* __restrict__ out, int N) {
    __shared__ int buf[ARENA_CAP];   // 6.9 KB
    __shared__ int srt[ARENA_CAP];   // 6.9 KB
    __shared__ int h[BNODES];
    __shared__ int cur[BNODES];
    __shared__ int rs[BNODES];
    __shared__ float dv[BNODES];
    int t = threadIdx.x;
    int b = blockIdx.x;
    int base = b * ARENA_CAP;
    int cnt = cursor[b] - base;
    if (cnt > ARENA_CAP) cnt = ARENA_CAP;  // by construction never binds
    if (t < BNODES) h[t] = 0;
    __syncthreads();
    for (int i = t; i < cnt; i += 256) {
        int p = __builtin_nontemporal_load(&binned[base + i]);
        buf[i] = p;
        atomicAdd(&h[p & (BNODES - 1)], 1);
    }
    __syncthreads();
    if (t < BNODES) {  // wave 0: shfl inclusive scan
        int v = h[t];
        int sc = v;
#pragma unroll
        for (int off = 1; off < BNODES; off <<= 1) {
            int u = __shfl_up(sc, off);
            if (t >= off) sc += u;
        }
        rs[t] = sc - v;   // exclusive prefix (node start in srt)
        cur[t] = sc - v;
        dv[t] = rsqrtf((float)(v + 1));
    }
    __syncthreads();
    for (int i = t; i < cnt; i += 256) {
        int p = buf[i];
        int pos = atomicAdd(&cur[p & (BNODES - 1)], 1);
        srt[pos] = (int)((unsigned)p >> BSHIFT);  // plain src index
    }
    __syncthreads();

    // ---- gather phase: 2 groups x 32 lanes, 8 loads in flight ----
    int lane = t & 63, wv = t >> 6;
    int g = lane >> 5;    // group 0..1
    int c = lane & 31;    // feature pair index (4 B per lane)
    float2 bb = ((const float2*)bs)[c];
#pragma unroll 1
    for (int nl = 0; nl < 16; nl++) {
        int ln = wv * 16 + nl;
        int node = (b << BSHIFT) + ln;
        int s = rs[ln];
        int deg = h[ln];
        float a0 = 0.f, a1 = 0.f, a2 = 0.f, a3 = 0.f;
        int k = 0;
        for (; k + 15 < deg; k += 16) {  // 16 edges, 8 loads in flight/group
            int p0 = srt[s + k + g];
            int p1 = srt[s + k + 2 + g];
            int p2 = srt[s + k + 4 + g];
            int p3 = srt[s + k + 6 + g];
            int p4 = srt[s + k + 8 + g];
            int p5 = srt[s + k + 10 + g];
            int p6 = srt[s + k + 12 + g];
            int p7 = srt[s + k + 14 + g];
            unsigned u0 = *(const unsigned*)&zbf[(size_t)p0 * D + 2 * c];
            unsigned u1 = *(const unsigned*)&zbf[(size_t)p1 * D + 2 * c];
            unsigned u2 = *(const unsigned*)&zbf[(size_t)p2 * D + 2 * c];
            unsigned u3 = *(const unsigned*)&zbf[(size_t)p3 * D + 2 * c];
            unsigned u4 = *(const unsigned*)&zbf[(size_t)p4 * D + 2 * c];
            unsigned u5 = *(const unsigned*)&zbf[(size_t)p5 * D + 2 * c];
            unsigned u6 = *(const unsigned*)&zbf[(size_t)p6 * D + 2 * c];
            unsigned u7 = *(const unsigned*)&zbf[(size_t)p7 * D + 2 * c];
            a0 += bflo(u0); a1 += bfhi(u0);
            a2 += bflo(u1); a3 += bfhi(u1);
            a0 += bflo(u2); a1 += bfhi(u2);
            a2 += bflo(u3); a3 += bfhi(u3);
            a0 += bflo(u4); a1 += bfhi(u4);
            a2 += bflo(u5); a3 += bfhi(u5);
            a0 += bflo(u6); a1 += bfhi(u6);
            a2 += bflo(u7); a3 += bfhi(u7);
        }
        for (; k + 7 < deg; k += 8) {  // 4 loads in flight
            int p0 = srt[s + k + g];
            int p1 = srt[s + k + 2 + g];
            int p2 = srt[s + k + 4 + g];
            int p3 = srt[s + k + 6 + g];
            unsigned u0 = *(const unsigned*)&zbf[(size_t)p0 * D + 2 * c];
            unsigned u1 = *(const unsigned*)&zbf[(size_t)p1 * D + 2 * c];
            unsigned u2 = *(const unsigned*)&zbf[(size_t)p2 * D + 2 * c];
            unsigned u3 = *(const unsigned*)&zbf[(size_t)p3 * D + 2 * c];
            a0 += bflo(u0); a1 += bfhi(u0);
            a2 += bflo(u1); a3 += bfhi(u1);
            a0 += bflo(u2); a1 += bfhi(u2);
            a2 += bflo(u3); a3 += bfhi(u3);
        }
        for (; k + 3 < deg; k += 4) {  // 2 loads in flight
            int p0 = srt[s + k + g];
            int p1 = srt[s + k + 2 + g];
            unsigned u0 = *(const unsigned*)&zbf[(size_t)p0 * D + 2 * c];
            unsigned u1 = *(const unsigned*)&zbf[(size_t)p1 * D + 2 * c];
            a0 += bflo(u0); a1 += bfhi(u0);
            a2 += bflo(u1); a3 += bfhi(u1);
        }
        for (; k + 1 < deg; k += 2) {  // pair
            int p0 = srt[s + k + g];
            unsigned u0 = *(const unsigned*)&zbf[(size_t)p0 * D + 2 * c];
            a0 += bflo(u0); a1 += bfhi(u0);
        }
        if (k < deg) {  // odd last edge (index valid for both groups)
            int p0 = srt[s + k];
            unsigned u0 = *(const unsigned*)&zbf[(size_t)p0 * D + 2 * c];
            if (g == 0) { a0 += bflo(u0); a1 += bfhi(u0); }
        }
        a0 += a2; a1 += a3;
        a0 += __shfl_xor(a0, 32);  // merge groups
        a1 += __shfl_xor(a1, 32);
        if (lane < 32 && node < N) {
            unsigned uz = *(const unsigned*)&zbf[(size_t)node * D + 2 * c];  // self
            float di = dv[ln];
            float2 o;
            o.x = di * (a0 + bflo(uz)) + bb.x;
            o.y = di * (a1 + bfhi(uz)) + bb.y;
            *(float2*)&out[(size_t)node * D + 2 * c] = o;
        }
    }
}

extern "C" void kernel_launch(void* const* d_in, const int* in_sizes, int n_in,
                              void* d_out, int out_size, void* d_ws, size_t ws_size,
                              hipStream_t stream) {
    const float* x = (const float*)d_in[0];
    const int* ei = (const int*)d_in[1];
    const float* W = (const float*)d_in[2];
    const float* b = (const float*)d_in[3];
    const float* A = (const float*)d_in[4];

    const int N = in_sizes[0] / D;
    const int E = in_sizes[1] / 2;
    const int* src = ei;
    const int* dst = ei + E;
    const int NBUCK = (N + BNODES - 1) >> BSHIFT;  // 1563; must be <=2048

    char* ws = (char*)d_ws;
    size_t off = 0;
    auto alloc = [&](size_t bytes) -> char* {
        char* p = ws + off;
        off = (off + bytes + 255) & ~(size_t)255;
        return p;
    };
    int* cursor = (int*)alloc((size_t)NBUCK * 4);
    float* M = (float*)alloc((size_t)D * D * 4);
    float* bs = (float*)alloc((size_t)D * 4);
    int* binned = (int*)alloc((size_t)NBUCK * ARENA_CAP * 4);  // 10.8 MB arena
    unsigned short* zbf = (unsigned short*)alloc((size_t)N * D * 2);
    (void)ws_size;  // total ~24 MiB (< 32.06 MiB proven safe)

    prep_kernel<<<16, 256, 0, stream>>>(W, b, A, M, bs, cursor, NBUCK);
    bin_kernel<<<(E + BIN_TILE - 1) / BIN_TILE, 1024, 0, stream>>>(src, dst, cursor, binned, E);
    zmat_kernel<<<NBUCK, 128, 0, stream>>>(x, M, binned, cursor, zbf, N);
    sg_kernel<<<NBUCK, 256, 0, stream>>>(zbf, binned, cursor, bs, (float*)d_out, N);
}

// Round 10
// 167.778 us; speedup vs baseline: 1.1501x; 1.1501x over previous
//
#include <hip/hip_runtime.h>
#include <hip/hip_bf16.h>

// CausalGraphLayer: out = [D^-1/2 (A+I) D^-1/2 (x W) + b] @ softmax(CA)
// Folded: M = W @ softmax(CA); bs = b @ softmax(CA);
//         z[i] = dinv[i] * (x[i] @ M)   (stored bf16)
//         out[d] = dinv[d] * (z[d] + sum_{(s,d) in E} z[s]) + bs
// N = 100000, E = 1600000, D = 64.
//
// Round 22: revert nt-STORES (round-9 regression +26us: WRITE_SIZE
// 47.6MB for 6.4MB payload = ~7x amplification — nt stores bypass L2
// write-combining, each scattered 4B store pushes a 32B sector to HBM;
// the L2 was already combining the scatter). KEEP nt-LOADS: measured
// bin FETCH 12.8 -> 6.3MB, stream-once data no longer pollutes L2.
// Everything else byte-identical to round 20/8's 167.2us kernel:
// prep v2 / bin v4(+ntload) / zmat v3(+ntload) / sg v2(+ntload).

#define D 64
#define BSHIFT 6
#define BNODES 64        // nodes per bucket
#define ARENA_CAP 1728   // arena slots per bucket (mean 1024, +22 sigma)
#define BIN_TILE 8192    // bin edges per block (196 blocks)

// f32 -> bf16 (round to nearest even)
__device__ __forceinline__ unsigned short f2bf(float f) {
    union { float f; unsigned int u; } c;
    c.f = f;
    unsigned int u = c.u;
    u += 0x7fffu + ((u >> 16) & 1u);
    return (unsigned short)(u >> 16);
}
// low/high bf16 of a packed uint -> f32
__device__ __forceinline__ float bflo(unsigned int u) {
    union { unsigned int u; float f; } c;
    c.u = u << 16;
    return c.f;
}
__device__ __forceinline__ float bfhi(unsigned int u) {
    union { unsigned int u; float f; } c;
    c.u = u & 0xffff0000u;
    return c.f;
}

// ---------------- K1: prep v2 — S = softmax(A); M = W@S; bs = b@S -----------
__global__ __launch_bounds__(256) void prep_kernel(const float* __restrict__ W,
                                                   const float* __restrict__ b,
                                                   const float* __restrict__ A,
                                                   float* __restrict__ M,
                                                   float* __restrict__ bs,
                                                   int* __restrict__ cursor, int nbuck) {
    __shared__ float S[D * D];
    int t = threadIdx.x;
    int gidx = blockIdx.x * 256 + t;
    if (gidx < nbuck) cursor[gidx] = gidx * ARENA_CAP;  // arena base
    int wv = t >> 6, lane = t & 63;
#pragma unroll 4
    for (int rr = 0; rr < 16; rr++) {
        int r = wv * 16 + rr;
        float a = A[r * D + lane];
        float m = a;
        for (int off = 32; off; off >>= 1) m = fmaxf(m, __shfl_xor(m, off));
        float p = __expf(a - m);
        float ssum = p;
        for (int off = 32; off; off >>= 1) ssum += __shfl_xor(ssum, off);
        S[r * D + lane] = p / ssum;
    }
    __syncthreads();
    int k = blockIdx.x * 4 + wv;  // M row (wave-uniform)
    float acc = 0.f;
    for (int d2 = 0; d2 < D; d2++) acc += W[k * D + d2] * S[d2 * D + lane];
    M[k * D + lane] = acc;
    if (blockIdx.x == 0 && t < D) {
        float a2 = 0.f;
        for (int d2 = 0; d2 < D; d2++) a2 += b[d2] * S[d2 * D + t];
        bs[t] = a2;
    }
}

// ---------------- K2: bin v4 — 1024 threads, nt loads, normal scatter -------
__global__ __launch_bounds__(1024) void bin_kernel(const int* __restrict__ src,
                                                   const int* __restrict__ dst,
                                                   int* __restrict__ cursor,
                                                   int* __restrict__ binned, int E) {
    __shared__ int h[2048];
    int t = threadIdx.x;
    for (int i = t; i < 2048; i += 1024) h[i] = 0;
    __syncthreads();
    int base = blockIdx.x * BIN_TILE;
    int pv[8], bk[8], rv[8];
#pragma unroll
    for (int k = 0; k < 8; k++) {
        int e = base + k * 1024 + t;
        if (e < E) {
            int s = __builtin_nontemporal_load(&src[e]);
            int d = __builtin_nontemporal_load(&dst[e]);
            bk[k] = (d >> BSHIFT) & 2047;
            pv[k] = (s << BSHIFT) | (d & (BNODES - 1));  // packed: src<<6 | dlocal
            rv[k] = atomicAdd(&h[bk[k]], 1);             // rank within (block,bucket)
        }
    }
    __syncthreads();
    for (int b2 = t; b2 < 2048; b2 += 1024) {
        int c = h[b2];
        if (c) h[b2] = atomicAdd(&cursor[b2], c);  // h[b2] := global write base
    }
    __syncthreads();
#pragma unroll
    for (int k = 0; k < 8; k++) {
        int e = base + k * 1024 + t;
        if (e < E) binned[h[bk[k]] + rv[k]] = pv[k];  // cacheable: L2 combines
    }
}

// ---------------- K3: zmat v3 — z = dinv*(x@M), fused degree histogram ------
__device__ __forceinline__ void fma4(float4& a, float xv, const float4& m) {
    a.x += xv * m.x; a.y += xv * m.y; a.z += xv * m.z; a.w += xv * m.w;
}
__global__ __launch_bounds__(128) void zmat_kernel(const float* __restrict__ x,
                                                   const float* __restrict__ M,
                                                   const int* __restrict__ binned,
                                                   const int* __restrict__ cursor,
                                                   unsigned short* __restrict__ zbf,
                                                   int N) {
    __shared__ float xs[64][D + 4];  // 17.4 KB
    __shared__ int h[BNODES];
    int t = threadIdx.x;
    int b = blockIdx.x;
    int row0 = b << 6;
    if (t < BNODES) h[t] = 0;
    __syncthreads();
    int abase = b * ARENA_CAP;
    int cnt = cursor[b] - abase;
    if (cnt > ARENA_CAP) cnt = ARENA_CAP;
    for (int i = t; i < cnt; i += 128)
        atomicAdd(&h[__builtin_nontemporal_load(&binned[abase + i]) & (BNODES - 1)], 1);
    for (int w = t; w < 1024; w += 128) {
        int r = w >> 4, c4 = (w & 15) << 2;
        int row = row0 + r;
        float4 v = make_float4(0.f, 0.f, 0.f, 0.f);
        if (row < N) v = *(const float4*)&x[(size_t)row * D + c4];
        *(float4*)&xs[r][c4] = v;
    }
    __syncthreads();
    int cg = t & 15, rg = t >> 4;    // rg 0..7
    int r0 = rg << 3, c0 = cg << 2;  // 8 rows, 4 cols per thread
    float4 acc[8];
#pragma unroll
    for (int rr = 0; rr < 8; rr++) acc[rr] = make_float4(0.f, 0.f, 0.f, 0.f);
#pragma unroll 2
    for (int k = 0; k < D; k += 4) {
        float4 m0 = *(const float4*)&M[(k + 0) * D + c0];
        float4 m1 = *(const float4*)&M[(k + 1) * D + c0];
        float4 m2 = *(const float4*)&M[(k + 2) * D + c0];
        float4 m3 = *(const float4*)&M[(k + 3) * D + c0];
#pragma unroll
        for (int rr = 0; rr < 8; rr++) {
            float4 xv = *(const float4*)&xs[r0 + rr][k];
            fma4(acc[rr], xv.x, m0);
            fma4(acc[rr], xv.y, m1);
            fma4(acc[rr], xv.z, m2);
            fma4(acc[rr], xv.w, m3);
        }
    }
#pragma unroll
    for (int rr = 0; rr < 8; rr++) {
        int row = row0 + r0 + rr;
        if (row < N) {
            float di = rsqrtf((float)(h[r0 + rr] + 1));
            ushort4 s;
            s.x = f2bf(di * acc[rr].x);
            s.y = f2bf(di * acc[rr].y);
            s.z = f2bf(di * acc[rr].z);
            s.w = f2bf(di * acc[rr].w);
            *(ushort4*)&zbf[(size_t)row * D + c0] = s;
        }
    }
}

// ---------------- K4: sg v2 — fused LDS sort + 8-in-flight gather -----------
__global__ __launch_bounds__(256) void sg_kernel(const unsigned short* __restrict__ zbf,
                                                 const int* __restrict__ binned,
                                                 const int* __restrict__ cursor,
                                                 const float* __restrict__ bs,
                                                 float* __restrict__ out, int N) {
    __shared__ int buf[ARENA_CAP];   // 6.9 KB
    __shared__ int srt[ARENA_CAP];   // 6.9 KB
    __shared__ int h[BNODES];
    __shared__ int cur[BNODES];
    __shared__ int rs[BNODES];
    __shared__ float dv[BNODES];
    int t = threadIdx.x;
    int b = blockIdx.x;
    int base = b * ARENA_CAP;
    int cnt = cursor[b] - base;
    if (cnt > ARENA_CAP) cnt = ARENA_CAP;  // by construction never binds
    if (t < BNODES) h[t] = 0;
    __syncthreads();
    for (int i = t; i < cnt; i += 256) {
        int p = __builtin_nontemporal_load(&binned[base + i]);
        buf[i] = p;
        atomicAdd(&h[p & (BNODES - 1)], 1);
    }
    __syncthreads();
    if (t < BNODES) {  // wave 0: shfl inclusive scan
        int v = h[t];
        int sc = v;
#pragma unroll
        for (int off = 1; off < BNODES; off <<= 1) {
            int u = __shfl_up(sc, off);
            if (t >= off) sc += u;
        }
        rs[t] = sc - v;   // exclusive prefix (node start in srt)
        cur[t] = sc - v;
        dv[t] = rsqrtf((float)(v + 1));
    }
    __syncthreads();
    for (int i = t; i < cnt; i += 256) {
        int p = buf[i];
        int pos = atomicAdd(&cur[p & (BNODES - 1)], 1);
        srt[pos] = (int)((unsigned)p >> BSHIFT);  // plain src index
    }
    __syncthreads();

    // ---- gather phase: 2 groups x 32 lanes, 8 loads in flight ----
    int lane = t & 63, wv = t >> 6;
    int g = lane >> 5;    // group 0..1
    int c = lane & 31;    // feature pair index (4 B per lane)
    float2 bb = ((const float2*)bs)[c];
#pragma unroll 1
    for (int nl = 0; nl < 16; nl++) {
        int ln = wv * 16 + nl;
        int node = (b << BSHIFT) + ln;
        int s = rs[ln];
        int deg = h[ln];
        float a0 = 0.f, a1 = 0.f, a2 = 0.f, a3 = 0.f;
        int k = 0;
        for (; k + 15 < deg; k += 16) {  // 16 edges, 8 loads in flight/group
            int p0 = srt[s + k + g];
            int p1 = srt[s + k + 2 + g];
            int p2 = srt[s + k + 4 + g];
            int p3 = srt[s + k + 6 + g];
            int p4 = srt[s + k + 8 + g];
            int p5 = srt[s + k + 10 + g];
            int p6 = srt[s + k + 12 + g];
            int p7 = srt[s + k + 14 + g];
            unsigned u0 = *(const unsigned*)&zbf[(size_t)p0 * D + 2 * c];
            unsigned u1 = *(const unsigned*)&zbf[(size_t)p1 * D + 2 * c];
            unsigned u2 = *(const unsigned*)&zbf[(size_t)p2 * D + 2 * c];
            unsigned u3 = *(const unsigned*)&zbf[(size_t)p3 * D + 2 * c];
            unsigned u4 = *(const unsigned*)&zbf[(size_t)p4 * D + 2 * c];
            unsigned u5 = *(const unsigned*)&zbf[(size_t)p5 * D + 2 * c];
            unsigned u6 = *(const unsigned*)&zbf[(size_t)p6 * D + 2 * c];
            unsigned u7 = *(const unsigned*)&zbf[(size_t)p7 * D + 2 * c];
            a0 += bflo(u0); a1 += bfhi(u0);
            a2 += bflo(u1); a3 += bfhi(u1);
            a0 += bflo(u2); a1 += bfhi(u2);
            a2 += bflo(u3); a3 += bfhi(u3);
            a0 += bflo(u4); a1 += bfhi(u4);
            a2 += bflo(u5); a3 += bfhi(u5);
            a0 += bflo(u6); a1 += bfhi(u6);
            a2 += bflo(u7); a3 += bfhi(u7);
        }
        for (; k + 7 < deg; k += 8) {  // 4 loads in flight
            int p0 = srt[s + k + g];
            int p1 = srt[s + k + 2 + g];
            int p2 = srt[s + k + 4 + g];
            int p3 = srt[s + k + 6 + g];
            unsigned u0 = *(const unsigned*)&zbf[(size_t)p0 * D + 2 * c];
            unsigned u1 = *(const unsigned*)&zbf[(size_t)p1 * D + 2 * c];
            unsigned u2 = *(const unsigned*)&zbf[(size_t)p2 * D + 2 * c];
            unsigned u3 = *(const unsigned*)&zbf[(size_t)p3 * D + 2 * c];
            a0 += bflo(u0); a1 += bfhi(u0);
            a2 += bflo(u1); a3 += bfhi(u1);
            a0 += bflo(u2); a1 += bfhi(u2);
            a2 += bflo(u3); a3 += bfhi(u3);
        }
        for (; k + 3 < deg; k += 4) {  // 2 loads in flight
            int p0 = srt[s + k + g];
            int p1 = srt[s + k + 2 + g];
            unsigned u0 = *(const unsigned*)&zbf[(size_t)p0 * D + 2 * c];
            unsigned u1 = *(const unsigned*)&zbf[(size_t)p1 * D + 2 * c];
            a0 += bflo(u0); a1 += bfhi(u0);
            a2 += bflo(u1); a3 += bfhi(u1);
        }
        for (; k + 1 < deg; k += 2) {  // pair
            int p0 = srt[s + k + g];
            unsigned u0 = *(const unsigned*)&zbf[(size_t)p0 * D + 2 * c];
            a0 += bflo(u0); a1 += bfhi(u0);
        }
        if (k < deg) {  // odd last edge (index valid for both groups)
            int p0 = srt[s + k];
            unsigned u0 = *(const unsigned*)&zbf[(size_t)p0 * D + 2 * c];
            if (g == 0) { a0 += bflo(u0); a1 += bfhi(u0); }
        }
        a0 += a2; a1 += a3;
        a0 += __shfl_xor(a0, 32);  // merge groups
        a1 += __shfl_xor(a1, 32);
        if (lane < 32 && node < N) {
            unsigned uz = *(const unsigned*)&zbf[(size_t)node * D + 2 * c];  // self
            float di = dv[ln];
            float2 o;
            o.x = di * (a0 + bflo(uz)) + bb.x;
            o.y = di * (a1 + bfhi(uz)) + bb.y;
            *(float2*)&out[(size_t)node * D + 2 * c] = o;
        }
    }
}

extern "C" void kernel_launch(void* const* d_in, const int* in_sizes, int n_in,
                              void* d_out, int out_size, void* d_ws, size_t ws_size,
                              hipStream_t stream) {
    const float* x = (const float*)d_in[0];
    const int* ei = (const int*)d_in[1];
    const float* W = (const float*)d_in[2];
    const float* b = (const float*)d_in[3];
    const float* A = (const float*)d_in[4];

    const int N = in_sizes[0] / D;
    const int E = in_sizes[1] / 2;
    const int* src = ei;
    const int* dst = ei + E;
    const int NBUCK = (N + BNODES - 1) >> BSHIFT;  // 1563; must be <=2048

    char* ws = (char*)d_ws;
    size_t off = 0;
    auto alloc = [&](size_t bytes) -> char* {
        char* p = ws + off;
        off = (off + bytes + 255) & ~(size_t)255;
        return p;
    };
    int* cursor = (int*)alloc((size_t)NBUCK * 4);
    float* M = (float*)alloc((size_t)D * D * 4);
    float* bs = (float*)alloc((size_t)D * 4);
    int* binned = (int*)alloc((size_t)NBUCK * ARENA_CAP * 4);  // 10.8 MB arena
    unsigned short* zbf = (unsigned short*)alloc((size_t)N * D * 2);
    (void)ws_size;  // total ~24 MiB (< 32.06 MiB proven safe)

    prep_kernel<<<16, 256, 0, stream>>>(W, b, A, M, bs, cursor, NBUCK);
    bin_kernel<<<(E + BIN_TILE - 1) / BIN_TILE, 1024, 0, stream>>>(src, dst, cursor, binned, E);
    zmat_kernel<<<NBUCK, 128, 0, stream>>>(x, M, binned, cursor, zbf, N);
    sg_kernel<<<NBUCK, 256, 0, stream>>>(zbf, binned, cursor, bs, (float*)d_out, N);
}